// Round 2
// 646.774 us; speedup vs baseline: 1.0426x; 1.0426x over previous
//
#include <hip/hip_runtime.h>
#include <math.h>

#define E_TOTAL 8
#define NUM_LOCAL 4
#define HIDDEN 1024
#define FFN 4096
#define CAP 2048

typedef unsigned short ushort_t;
typedef __attribute__((ext_vector_type(8))) short short8;     // 8 bf16 (4 VGPRs)
typedef __attribute__((ext_vector_type(8))) unsigned short u16x8;
typedef __attribute__((ext_vector_type(4))) float f32x4;      // MFMA accumulator

__device__ __forceinline__ unsigned short f2bf(float f) {
  unsigned int u = __float_as_uint(f);
  u += 0x7FFFu + ((u >> 16) & 1u);   // round-to-nearest-even
  return (unsigned short)(u >> 16);
}

__device__ __forceinline__ void gload_lds16(const void* g, void* l) {
  __builtin_amdgcn_global_load_lds(
      (const __attribute__((address_space(1))) void*)g,
      (__attribute__((address_space(3))) void*)l,
      16, 0, 0);
}

// Branch-free GELU: erf via Abramowitz-Stegun 7.1.26 (|abs err| <= 1.5e-7,
// far below bf16 output rounding). Replaces branchy libm erff (~3x cheaper).
__device__ __forceinline__ float fast_gelu(float v) {
  const float x = v * 0.70710678118654752f;
  const float ax = fabsf(x);
  const float t = 1.f / (1.f + 0.3275911f * ax);
  const float p =
      t * (0.254829592f +
           t * (-0.284496736f +
                t * (1.421413741f + t * (-1.453152027f + t * 1.061405429f))));
  float erfv = 1.f - p * __expf(-ax * ax);
  erfv = copysignf(erfv, x);
  return 0.5f * v * (1.f + erfv);
}

// fp32 -> bf16 bulk convert: 8 elements/lane (2x float4 in, 1x 16B store out)
__global__ __launch_bounds__(256) void cvt_kernel(const float4* __restrict__ s,
                                                  u16x8* __restrict__ d) {
  const size_t i = (size_t)blockIdx.x * 256 + threadIdx.x;
  float4 a = s[2 * i], b = s[2 * i + 1];
  u16x8 o;
  o[0] = f2bf(a.x); o[1] = f2bf(a.y); o[2] = f2bf(a.z); o[3] = f2bf(a.w);
  o[4] = f2bf(b.x); o[5] = f2bf(b.y); o[6] = f2bf(b.z); o[7] = f2bf(b.w);
  d[i] = o;
}

// Stage one 128x64 half-tile (16KB) with 2 global_load_lds(16B)/thread.
// LDS layout is linear; the XOR swizzle is applied on the SOURCE k-chunk
// (both-sides-or-neither rule): linear slot s of row r holds chunk s^(r&7).
template <int KD>
__device__ __forceinline__ void stage_half(const ushort_t* g, char* dst,
                                           int tid) {
  gload_lds16(g, dst + tid * 16);                         // rows 0-63 of half
  gload_lds16(g + (size_t)64 * KD, dst + 8192 + tid * 16);// rows 64-127
}

#define LOAD_A4(F0)                                                          \
  do {                                                                       \
    _Pragma("unroll") for (int ks = 0; ks < 2; ++ks)                         \
    _Pragma("unroll") for (int i = 0; i < 4; ++i)                            \
      af[i][ks] = *(const short8*)(sAc + aoff[ks] + ((F0) + i) * 2048);      \
  } while (0)

#define LOAD_B2(J0)                                                          \
  do {                                                                       \
    _Pragma("unroll") for (int ks = 0; ks < 2; ++ks)                         \
    _Pragma("unroll") for (int j = 0; j < 2; ++j)                            \
      bf[(J0) + j][ks] =                                                     \
          *(const short8*)(sBc + boff[ks] + ((J0) + j) * 2048);              \
  } while (0)

#define MFMA16(MI0, NJ0)                                                     \
  do {                                                                       \
    __builtin_amdgcn_s_setprio(1);                                           \
    _Pragma("unroll") for (int ks = 0; ks < 2; ++ks)                         \
    _Pragma("unroll") for (int i = 0; i < 4; ++i)                            \
    _Pragma("unroll") for (int j = 0; j < 2; ++j)                            \
      acc[(MI0) + i][(NJ0) + j] = __builtin_amdgcn_mfma_f32_16x16x32_bf16(   \
          af[i][ks], bf[(NJ0) + j][ks], acc[(MI0) + i][(NJ0) + j], 0, 0, 0); \
    __builtin_amdgcn_s_setprio(0);                                           \
  } while (0)

// barrier, then force the ds_reads issued this phase to be complete before
// the MFMAs (rule #18: sched_barrier(0) after inline-asm lgkmcnt, else the
// compiler hoists register-only MFMAs past the wait).
#define PHASE_SYNC()                                                         \
  __builtin_amdgcn_s_barrier();                                              \
  asm volatile("s_waitcnt lgkmcnt(0)" ::: "memory");                         \
  __builtin_amdgcn_sched_barrier(0)

// 256x256-tile, BK=64, 8-wave (2M x 4N), 8-phase counted-vmcnt NT GEMM.
// A [E][M][K] bf16 row-major, B [E][N][K] bf16 row-major (B^T input).
//
// Per K-tile t (buffer t&1), 4 phases; per-wave C = 128x64 = 8x4 frags:
//   p0: ds_read A frags 0-3 + B frags 0-1 | stage A0(t+1)->buf(t+1)  | MFMA mi0-3 x nj0-1
//   p1: ds_read B frags 2-3               | stage A1(t+1)->buf(t+1)  | MFMA mi0-3 x nj2-3
//   p2: ds_read A frags 4-7               | stage B0(t+2)->buf(t)    | MFMA mi4-7 x nj0-1
//   p3:                                   | stage B1(t+2)->buf(t)    | MFMA mi4-7 x nj2-3
//       vmcnt(4) (B(t+2) stays in flight) before the tile-boundary barrier.
// Race-freedom: every staged half overwrites a region whose last ds_read is
// >=1 barrier earlier (A(t-1) last read p2 of t-1; B(t) last read p1 of t).
// vmcnt(4) at the boundary guarantees all of tile t+1 has landed while
// keeping 2 half-tiles (4 loads) in flight across barriers (T4).
template <int M, int N, int K, bool GELU_OUT>
__global__ __launch_bounds__(512, 2) void gemm_nt8(
    const ushort_t* __restrict__ A, const ushort_t* __restrict__ B,
    void* __restrict__ Cout, const float* __restrict__ ot, int d0) {
  __shared__ char sA[2][32768];   // [buf][256 rows][64 k] bf16, 64KB
  __shared__ char sB[2][32768];   // 128KB total -> 1 block/CU
  constexpr int NT = K / 64;
  static_assert(NT >= 2, "pipeline needs >=2 K-tiles");

  const int e = blockIdx.z;
  const int bm = blockIdx.x * 256;
  const int bn = blockIdx.y * 256;
  const int tid = threadIdx.x;
  const int lane = tid & 63, wv = tid >> 6;
  const int wr = wv >> 2, wc = wv & 3;         // wave: 2M x 4N grid
  const int quad = lane >> 4, l16 = lane & 15;
  const int swz = l16 & 7;

  // staging source: thread covers row rp (of 64 per load), source chunk cs
  const int rp = tid >> 3;
  const int cs = (tid & 7) ^ (rp & 7);
  const ushort_t* gA = A + (size_t)e * M * K + (size_t)(bm + rp) * K + cs * 8;
  const ushort_t* gB = B + (size_t)e * N * K + (size_t)(bn + rp) * K + cs * 8;

  // ds_read byte offsets (swizzled): row*128 + (chunk ^ (row&7))*16
  int aoff[2], boff[2];
#pragma unroll
  for (int ks = 0; ks < 2; ++ks) {
    aoff[ks] = (wr * 128 + l16) * 128 + (((ks * 4 + quad) ^ swz) << 4);
    boff[ks] = (wc * 64 + l16) * 128 + (((ks * 4 + quad) ^ swz) << 4);
  }

  f32x4 acc[8][4];
#pragma unroll
  for (int i = 0; i < 8; ++i)
#pragma unroll
    for (int j = 0; j < 4; ++j) {
      f32x4 z = {0.f, 0.f, 0.f, 0.f};
      acc[i][j] = z;
    }

  short8 af[4][2];   // current A M-quad (4 frags x 2 k-slices)
  short8 bf[4][2];   // all 4 B N-frags, persist the whole tile

  // ---- prologue: tile0 fully + B halves of tile1 (= "tile -1 p2/p3") ----
  stage_half<K>(gA, sA[0], tid);
  stage_half<K>(gA + (size_t)128 * K, sA[0] + 16384, tid);
  stage_half<K>(gB, sB[0], tid);
  stage_half<K>(gB + (size_t)128 * K, sB[0] + 16384, tid);
  stage_half<K>(gB + 64, sB[1], tid);
  stage_half<K>(gB + (size_t)128 * K + 64, sB[1] + 16384, tid);
  asm volatile("s_waitcnt vmcnt(4)" ::: "memory");  // tile0 landed; B(1) in flight
  __builtin_amdgcn_sched_barrier(0);
  __builtin_amdgcn_s_barrier();

#pragma unroll 2
  for (int t = 0; t < NT; ++t) {
    char* sAc = sA[t & 1];
    char* sBc = sB[t & 1];
    char* sAn = sA[(t + 1) & 1];
    const size_t ko1 = (size_t)(t + 1) * 64;
    const size_t ko2 = (size_t)(t + 2) * 64;

    // ---- phase 0 ----
    LOAD_A4(0);
    LOAD_B2(0);
    if (t + 1 < NT) stage_half<K>(gA + ko1, sAn, tid);
    PHASE_SYNC();
    MFMA16(0, 0);
    __builtin_amdgcn_s_barrier();

    // ---- phase 1 ----
    LOAD_B2(2);
    if (t + 1 < NT) stage_half<K>(gA + (size_t)128 * K + ko1, sAn + 16384, tid);
    PHASE_SYNC();
    MFMA16(0, 2);
    __builtin_amdgcn_s_barrier();

    // ---- phase 2 ----
    LOAD_A4(4);
    if (t + 2 < NT) stage_half<K>(gB + ko2, sBc, tid);
    PHASE_SYNC();
    MFMA16(4, 0);
    __builtin_amdgcn_s_barrier();

    // ---- phase 3 ----
    if (t + 2 < NT) stage_half<K>(gB + (size_t)128 * K + ko2, sBc + 16384, tid);
    PHASE_SYNC();
    MFMA16(4, 2);
    // tile boundary: everything tile t+1 needs must be landed; keep the
    // newest 4 loads (B halves of t+2) in flight. Tail tiles drain fully.
    if (t + 2 < NT) {
      asm volatile("s_waitcnt vmcnt(4)" ::: "memory");
    } else {
      asm volatile("s_waitcnt vmcnt(0)" ::: "memory");
    }
    __builtin_amdgcn_sched_barrier(0);
    __builtin_amdgcn_s_barrier();
  }

  // ---- epilogue: C/D layout col=lane&15, row=quad*4+reg (m89-verified) ----
  if (GELU_OUT) {
    ushort_t* C = (ushort_t*)Cout + (size_t)e * M * N +
                  (size_t)(bm + wr * 128) * N + (bn + wc * 64);
#pragma unroll
    for (int mi = 0; mi < 8; ++mi)
#pragma unroll
      for (int r = 0; r < 4; ++r) {
        const int row = mi * 16 + quad * 4 + r;
#pragma unroll
        for (int ni = 0; ni < 4; ++ni)
          C[(size_t)row * N + ni * 16 + l16] = f2bf(fast_gelu(acc[mi][ni][r]));
      }
  } else {
    float mask = 1.f;
    if (e >= NUM_LOCAL) {
      float s = 0.f;
      for (int b = 0; b < d0; ++b) s += ot[b * E_TOTAL + e];
      mask = (s != 0.f) ? 1.f : 0.f;
    }
    float* C = (float*)Cout + (size_t)e * M * N +
               (size_t)(bm + wr * 128) * N + (bn + wc * 64);
#pragma unroll
    for (int mi = 0; mi < 8; ++mi)
#pragma unroll
      for (int r = 0; r < 4; ++r) {
        const int row = mi * 16 + quad * 4 + r;
#pragma unroll
        for (int ni = 0; ni < 4; ++ni)
          C[(size_t)row * N + ni * 16 + l16] = acc[mi][ni][r] * mask;
      }
  }
}

extern "C" void kernel_launch(void* const* d_in, const int* in_sizes, int n_in,
                              void* d_out, int out_size, void* d_ws,
                              size_t ws_size, hipStream_t stream) {
  const float* ot = (const float*)d_in[0];   // [D0][E] gating activity
  const float* x  = (const float*)d_in[1];   // [D0][E][CAP][HIDDEN] fp32
  const float* w0 = (const float*)d_in[2];   // [E][FFN][HIDDEN] fp32
  const float* w3 = (const float*)d_in[3];   // [E][HIDDEN][FFN] fp32
  const int d0 = in_sizes[0] / E_TOTAL;

  // Workspace layout (224 MB):
  //   [0,32MB)    x_bf16   -- later overwritten by w3_bf16
  //   [32,96MB)   w0_bf16
  //   [96,224MB)  h bf16 [E][CAP][FFN]
  char* ws = (char*)d_ws;
  ushort_t* xb  = (ushort_t*)ws;
  ushort_t* w0b = (ushort_t*)(ws + (size_t)32 * 1024 * 1024);
  ushort_t* w3b = (ushort_t*)ws;  // reuses x/w0 region AFTER gemm1 (stream order)
  ushort_t* h   = (ushort_t*)(ws + (size_t)96 * 1024 * 1024);

  const int nx = E_TOTAL * CAP * HIDDEN;  // 16.8M elements
  const int nw = E_TOTAL * FFN * HIDDEN;  // 33.6M elements

  cvt_kernel<<<nx / (256 * 8), 256, 0, stream>>>((const float4*)x, (u16x8*)xb);
  cvt_kernel<<<nw / (256 * 8), 256, 0, stream>>>((const float4*)w0, (u16x8*)w0b);

  // GEMM1: h[e] = GELU(x[e] (2048x1024) * w0[e]^T (1024x4096)) -> bf16
  gemm_nt8<CAP, FFN, HIDDEN, true>
      <<<dim3(CAP / 256, FFN / 256, E_TOTAL), 512, 0, stream>>>(
          xb, w0b, h, nullptr, d0);

  cvt_kernel<<<nw / (256 * 8), 256, 0, stream>>>((const float4*)w3, (u16x8*)w3b);

  // GEMM2: out[e] = h[e] (2048x4096) * w3[e]^T (4096x1024), masked, fp32
  gemm_nt8<CAP, HIDDEN, FFN, false>
      <<<dim3(CAP / 256, HIDDEN / 256, E_TOTAL), 512, 0, stream>>>(
          h, w3b, d_out, ot, d0);
}

// Round 3
// 631.991 us; speedup vs baseline: 1.0670x; 1.0234x over previous
//
#include <hip/hip_runtime.h>
#include <math.h>

#define E_TOTAL 8
#define NUM_LOCAL 4
#define HIDDEN 1024
#define FFN 4096
#define CAP 2048

typedef unsigned short ushort_t;
typedef __attribute__((ext_vector_type(8))) short short8;     // 8 bf16 (4 VGPRs)
typedef __attribute__((ext_vector_type(8))) unsigned short u16x8;
typedef __attribute__((ext_vector_type(4))) float f32x4;      // MFMA accumulator

__device__ __forceinline__ unsigned short f2bf(float f) {
  unsigned int u = __float_as_uint(f);
  u += 0x7FFFu + ((u >> 16) & 1u);   // round-to-nearest-even
  return (unsigned short)(u >> 16);
}

__device__ __forceinline__ void gload_lds16(const void* g, void* l) {
  __builtin_amdgcn_global_load_lds(
      (const __attribute__((address_space(1))) void*)g,
      (__attribute__((address_space(3))) void*)l,
      16, 0, 0);
}

// Branch-free GELU: erf via Abramowitz-Stegun 7.1.26 (|abs err| <= 1.5e-7,
// far below bf16 output rounding). Replaces branchy libm erff.
__device__ __forceinline__ float fast_gelu(float v) {
  const float x = v * 0.70710678118654752f;
  const float ax = fabsf(x);
  const float t = 1.f / (1.f + 0.3275911f * ax);
  const float p =
      t * (0.254829592f +
           t * (-0.284496736f +
                t * (1.421413741f + t * (-1.453152027f + t * 1.061405429f))));
  float erfv = 1.f - p * __expf(-ax * ax);
  erfv = copysignf(erfv, x);
  return 0.5f * v * (1.f + erfv);
}

// fp32 -> bf16 bulk convert: 8 elements/lane (2x float4 in, 1x 16B store out)
__global__ __launch_bounds__(256) void cvt_kernel(const float4* __restrict__ s,
                                                  u16x8* __restrict__ d) {
  const size_t i = (size_t)blockIdx.x * 256 + threadIdx.x;
  float4 a = s[2 * i], b = s[2 * i + 1];
  u16x8 o;
  o[0] = f2bf(a.x); o[1] = f2bf(a.y); o[2] = f2bf(a.z); o[3] = f2bf(a.w);
  o[4] = f2bf(b.x); o[5] = f2bf(b.y); o[6] = f2bf(b.z); o[7] = f2bf(b.w);
  d[i] = o;
}

// ============================================================================
// GEMM1 kernel: proven 128x128-tile 2-phase structure (round-0, 179us) with
// fast_gelu epilogue + XCD-chunked block swizzle.
// NT GEMM: A [E][M][K] bf16 row-major, B [E][N][K] bf16 row-major (B^T).
// LDS rotate swizzle: slot s of row r holds global k-chunk (s + (r&7)) & 7.
// ============================================================================
template <int M, int N, int K, bool GELU_OUT>
__global__ __launch_bounds__(256, 2) void gemm_nt(
    const ushort_t* __restrict__ A, const ushort_t* __restrict__ B,
    void* __restrict__ Cout, const float* __restrict__ ot, int d0) {
  __shared__ ushort_t lds_a[128 * 64];  // 16 KB, row-major [128][64], swizzled
  __shared__ ushort_t lds_b[128 * 64];

  // XCD-chunked swizzle (T1): hw xcd = flat%8; give each XCD a contiguous
  // slab of (e, n-panel, m-panel) lex order -> co-resident blocks share
  // B panels 16-way and A panels within a slab in one L2.
  constexpr int GX = M / 128, GY = N / 128;
  constexpr int NWG = GX * GY * E_TOTAL;
  static_assert(NWG % 8 == 0, "bijective swizzle needs nwg%8==0");
  int dfl = blockIdx.x + GX * (blockIdx.y + GY * blockIdx.z);
  dfl = (dfl & 7) * (NWG / 8) + (dfl >> 3);
  const int e = dfl / (GX * GY);
  const int rem = dfl % (GX * GY);
  const int bm = (rem % GX) * 128;
  const int bn = (rem / GX) * 128;

  const int t = threadIdx.x;
  const int wave = t >> 6, lane = t & 63;
  const int wr = wave >> 1, wc = wave & 1;     // wave quadrant in 128x128
  const int quad = lane >> 4, l16 = lane & 15;
  const int r8 = lane >> 3;                    // staging: row within 8-row group
  const int s8 = lane & 7;                     // staging: LDS slot within row
  const int g8 = (s8 + r8) & 7;                // staging: swizzled global chunk

  const ushort_t* Ag = A + (size_t)e * M * K + (size_t)(bm + r8) * K + g8 * 8;
  const ushort_t* Bg = B + (size_t)e * N * K + (size_t)(bn + r8) * K + g8 * 8;

  f32x4 acc[4][4];
#pragma unroll
  for (int i = 0; i < 4; ++i)
#pragma unroll
    for (int j = 0; j < 4; ++j) {
      f32x4 z = {0.f, 0.f, 0.f, 0.f};
      acc[i][j] = z;
    }

  for (int kb = 0; kb < K / 64; ++kb) {
    const size_t ko = (size_t)kb * 64;
#pragma unroll
    for (int j = 0; j < 4; ++j) {
      const int R = (j * 4 + wave) * 8;
      gload_lds16(Ag + ko + (size_t)R * K, &lds_a[R * 64]);
      gload_lds16(Bg + ko + (size_t)R * K, &lds_b[R * 64]);
    }
    __syncthreads();

#pragma unroll
    for (int ks = 0; ks < 2; ++ks) {
      short8 af[4], bfr[4];
      const int c = ks * 4 + quad;
#pragma unroll
      for (int i = 0; i < 4; ++i) {
        const int ra = wr * 64 + i * 16 + l16;
        const int rb = wc * 64 + i * 16 + l16;
        af[i]  = *(const short8*)&lds_a[ra * 64 + ((c - ra) & 7) * 8];
        bfr[i] = *(const short8*)&lds_b[rb * 64 + ((c - rb) & 7) * 8];
      }
#pragma unroll
      for (int mi = 0; mi < 4; ++mi)
#pragma unroll
        for (int ni = 0; ni < 4; ++ni)
          acc[mi][ni] = __builtin_amdgcn_mfma_f32_16x16x32_bf16(
              af[mi], bfr[ni], acc[mi][ni], 0, 0, 0);
    }
    __syncthreads();
  }

  // epilogue: C/D layout col=lane&15, row=quad*4+reg (m89-verified)
  if (GELU_OUT) {
    ushort_t* C = (ushort_t*)Cout + (size_t)e * M * N +
                  (size_t)(bm + wr * 64) * N + (bn + wc * 64);
#pragma unroll
    for (int mi = 0; mi < 4; ++mi)
#pragma unroll
      for (int r = 0; r < 4; ++r) {
        const int row = mi * 16 + quad * 4 + r;
#pragma unroll
        for (int ni = 0; ni < 4; ++ni)
          C[(size_t)row * N + ni * 16 + l16] = f2bf(fast_gelu(acc[mi][ni][r]));
      }
  } else {
    float mask = 1.f;
    if (e >= NUM_LOCAL) {
      float s = 0.f;
      for (int b = 0; b < d0; ++b) s += ot[b * E_TOTAL + e];
      mask = (s != 0.f) ? 1.f : 0.f;
    }
    float* C = (float*)Cout + (size_t)e * M * N +
               (size_t)(bm + wr * 64) * N + (bn + wc * 64);
#pragma unroll
    for (int mi = 0; mi < 4; ++mi)
#pragma unroll
      for (int r = 0; r < 4; ++r) {
        const int row = mi * 16 + quad * 4 + r;
#pragma unroll
        for (int ni = 0; ni < 4; ++ni)
          C[(size_t)row * N + ni * 16 + l16] = acc[mi][ni][r] * mask;
      }
  }
}

// ============================================================================
// GEMM2 kernel: 256x256-tile, BK=64, 8-wave, 8-phase counted-vmcnt (round-2,
// est. ~132us on K=4096) + XCD-chunked swizzle (one expert per XCD).
// ============================================================================
template <int KD>
__device__ __forceinline__ void stage_half(const ushort_t* g, char* dst,
                                           int tid) {
  gload_lds16(g, dst + tid * 16);                         // rows 0-63 of half
  gload_lds16(g + (size_t)64 * KD, dst + 8192 + tid * 16);// rows 64-127
}

#define LOAD_A4(F0)                                                          \
  do {                                                                       \
    _Pragma("unroll") for (int ks = 0; ks < 2; ++ks)                         \
    _Pragma("unroll") for (int i = 0; i < 4; ++i)                            \
      af[i][ks] = *(const short8*)(sAc + aoff[ks] + ((F0) + i) * 2048);      \
  } while (0)

#define LOAD_B2(J0)                                                          \
  do {                                                                       \
    _Pragma("unroll") for (int ks = 0; ks < 2; ++ks)                         \
    _Pragma("unroll") for (int j = 0; j < 2; ++j)                            \
      bf[(J0) + j][ks] =                                                     \
          *(const short8*)(sBc + boff[ks] + ((J0) + j) * 2048);              \
  } while (0)

#define MFMA16(MI0, NJ0)                                                     \
  do {                                                                       \
    __builtin_amdgcn_s_setprio(1);                                           \
    _Pragma("unroll") for (int ks = 0; ks < 2; ++ks)                         \
    _Pragma("unroll") for (int i = 0; i < 4; ++i)                            \
    _Pragma("unroll") for (int j = 0; j < 2; ++j)                            \
      acc[(MI0) + i][(NJ0) + j] = __builtin_amdgcn_mfma_f32_16x16x32_bf16(   \
          af[i][ks], bf[(NJ0) + j][ks], acc[(MI0) + i][(NJ0) + j], 0, 0, 0); \
    __builtin_amdgcn_s_setprio(0);                                           \
  } while (0)

#define PHASE_SYNC()                                                         \
  __builtin_amdgcn_s_barrier();                                              \
  asm volatile("s_waitcnt lgkmcnt(0)" ::: "memory");                         \
  __builtin_amdgcn_sched_barrier(0)

template <int M, int N, int K, bool GELU_OUT>
__global__ __launch_bounds__(512, 2) void gemm_nt8(
    const ushort_t* __restrict__ A, const ushort_t* __restrict__ B,
    void* __restrict__ Cout, const float* __restrict__ ot, int d0) {
  __shared__ char sA[2][32768];   // [buf][256 rows][64 k] bf16, 64KB
  __shared__ char sB[2][32768];   // 128KB total -> 1 block/CU
  constexpr int NT = K / 64;
  static_assert(NT >= 2, "pipeline needs >=2 K-tiles");

  constexpr int GX = M / 256, GY = N / 256;
  constexpr int NWG = GX * GY * E_TOTAL;
  static_assert(NWG % 8 == 0, "bijective swizzle needs nwg%8==0");
  int dfl = blockIdx.x + GX * (blockIdx.y + GY * blockIdx.z);
  dfl = (dfl & 7) * (NWG / 8) + (dfl >> 3);
  const int e = dfl / (GX * GY);
  const int rem = dfl % (GX * GY);
  const int bm = (rem % GX) * 256;
  const int bn = (rem / GX) * 256;

  const int tid = threadIdx.x;
  const int lane = tid & 63, wv = tid >> 6;
  const int wr = wv >> 2, wc = wv & 3;         // wave: 2M x 4N grid
  const int quad = lane >> 4, l16 = lane & 15;
  const int swz = l16 & 7;

  const int rp = tid >> 3;
  const int cs = (tid & 7) ^ (rp & 7);
  const ushort_t* gA = A + (size_t)e * M * K + (size_t)(bm + rp) * K + cs * 8;
  const ushort_t* gB = B + (size_t)e * N * K + (size_t)(bn + rp) * K + cs * 8;

  int aoff[2], boff[2];
#pragma unroll
  for (int ks = 0; ks < 2; ++ks) {
    aoff[ks] = (wr * 128 + l16) * 128 + (((ks * 4 + quad) ^ swz) << 4);
    boff[ks] = (wc * 64 + l16) * 128 + (((ks * 4 + quad) ^ swz) << 4);
  }

  f32x4 acc[8][4];
#pragma unroll
  for (int i = 0; i < 8; ++i)
#pragma unroll
    for (int j = 0; j < 4; ++j) {
      f32x4 z = {0.f, 0.f, 0.f, 0.f};
      acc[i][j] = z;
    }

  short8 af[4][2];
  short8 bf[4][2];

  // prologue: tile0 fully + B halves of tile1
  stage_half<K>(gA, sA[0], tid);
  stage_half<K>(gA + (size_t)128 * K, sA[0] + 16384, tid);
  stage_half<K>(gB, sB[0], tid);
  stage_half<K>(gB + (size_t)128 * K, sB[0] + 16384, tid);
  stage_half<K>(gB + 64, sB[1], tid);
  stage_half<K>(gB + (size_t)128 * K + 64, sB[1] + 16384, tid);
  asm volatile("s_waitcnt vmcnt(4)" ::: "memory");
  __builtin_amdgcn_sched_barrier(0);
  __builtin_amdgcn_s_barrier();

#pragma unroll 2
  for (int t = 0; t < NT; ++t) {
    char* sAc = sA[t & 1];
    char* sBc = sB[t & 1];
    char* sAn = sA[(t + 1) & 1];
    const size_t ko1 = (size_t)(t + 1) * 64;
    const size_t ko2 = (size_t)(t + 2) * 64;

    // phase 0
    LOAD_A4(0);
    LOAD_B2(0);
    if (t + 1 < NT) stage_half<K>(gA + ko1, sAn, tid);
    PHASE_SYNC();
    MFMA16(0, 0);
    __builtin_amdgcn_s_barrier();

    // phase 1
    LOAD_B2(2);
    if (t + 1 < NT) stage_half<K>(gA + (size_t)128 * K + ko1, sAn + 16384, tid);
    PHASE_SYNC();
    MFMA16(0, 2);
    __builtin_amdgcn_s_barrier();

    // phase 2
    LOAD_A4(4);
    if (t + 2 < NT) stage_half<K>(gB + ko2, sBc, tid);
    PHASE_SYNC();
    MFMA16(4, 0);
    __builtin_amdgcn_s_barrier();

    // phase 3
    if (t + 2 < NT) stage_half<K>(gB + (size_t)128 * K + ko2, sBc + 16384, tid);
    PHASE_SYNC();
    MFMA16(4, 2);
    if (t + 2 < NT) {
      asm volatile("s_waitcnt vmcnt(4)" ::: "memory");
    } else {
      asm volatile("s_waitcnt vmcnt(0)" ::: "memory");
    }
    __builtin_amdgcn_sched_barrier(0);
    __builtin_amdgcn_s_barrier();
  }

  // epilogue
  if (GELU_OUT) {
    ushort_t* C = (ushort_t*)Cout + (size_t)e * M * N +
                  (size_t)(bm + wr * 128) * N + (bn + wc * 64);
#pragma unroll
    for (int mi = 0; mi < 8; ++mi)
#pragma unroll
      for (int r = 0; r < 4; ++r) {
        const int row = mi * 16 + quad * 4 + r;
#pragma unroll
        for (int ni = 0; ni < 4; ++ni)
          C[(size_t)row * N + ni * 16 + l16] = f2bf(fast_gelu(acc[mi][ni][r]));
      }
  } else {
    float mask = 1.f;
    if (e >= NUM_LOCAL) {
      float s = 0.f;
      for (int b = 0; b < d0; ++b) s += ot[b * E_TOTAL + e];
      mask = (s != 0.f) ? 1.f : 0.f;
    }
    float* C = (float*)Cout + (size_t)e * M * N +
               (size_t)(bm + wr * 128) * N + (bn + wc * 64);
#pragma unroll
    for (int mi = 0; mi < 8; ++mi)
#pragma unroll
      for (int r = 0; r < 4; ++r) {
        const int row = mi * 16 + quad * 4 + r;
#pragma unroll
        for (int ni = 0; ni < 4; ++ni)
          C[(size_t)row * N + ni * 16 + l16] = acc[mi][ni][r] * mask;
      }
  }
}

extern "C" void kernel_launch(void* const* d_in, const int* in_sizes, int n_in,
                              void* d_out, int out_size, void* d_ws,
                              size_t ws_size, hipStream_t stream) {
  const float* ot = (const float*)d_in[0];   // [D0][E] gating activity
  const float* x  = (const float*)d_in[1];   // [D0][E][CAP][HIDDEN] fp32
  const float* w0 = (const float*)d_in[2];   // [E][FFN][HIDDEN] fp32
  const float* w3 = (const float*)d_in[3];   // [E][HIDDEN][FFN] fp32
  const int d0 = in_sizes[0] / E_TOTAL;

  // Workspace layout (224 MB):
  //   [0,32MB)    x_bf16   -- later overwritten by w3_bf16
  //   [32,96MB)   w0_bf16
  //   [96,224MB)  h bf16 [E][CAP][FFN]
  char* ws = (char*)d_ws;
  ushort_t* xb  = (ushort_t*)ws;
  ushort_t* w0b = (ushort_t*)(ws + (size_t)32 * 1024 * 1024);
  ushort_t* w3b = (ushort_t*)ws;  // reuses x/w0 region AFTER gemm1 (stream order)
  ushort_t* h   = (ushort_t*)(ws + (size_t)96 * 1024 * 1024);

  const int nx = E_TOTAL * CAP * HIDDEN;  // 16.8M elements
  const int nw = E_TOTAL * FFN * HIDDEN;  // 33.6M elements

  cvt_kernel<<<nx / (256 * 8), 256, 0, stream>>>((const float4*)x, (u16x8*)xb);
  cvt_kernel<<<nw / (256 * 8), 256, 0, stream>>>((const float4*)w0, (u16x8*)w0b);

  // GEMM1: h[e] = GELU(x[e] (2048x1024) * w0[e]^T (1024x4096)) -> bf16
  // 128^2 2-phase kernel: best measured for the short-K, 4-round shape.
  gemm_nt<CAP, FFN, HIDDEN, true>
      <<<dim3(CAP / 128, FFN / 128, E_TOTAL), 256, 0, stream>>>(
          xb, w0b, h, nullptr, d0);

  cvt_kernel<<<nw / (256 * 8), 256, 0, stream>>>((const float4*)w3, (u16x8*)w3b);

  // GEMM2: out[e] = h[e] (2048x4096) * w3[e]^T (4096x1024), masked, fp32
  // 256^2 8-phase kernel: wins in the long-K steady state.
  gemm_nt8<CAP, HIDDEN, FFN, false>
      <<<dim3(CAP / 256, HIDDEN / 256, E_TOTAL), 512, 0, stream>>>(
          h, w3b, d_out, ot, d0);
}